// Round 6
// baseline (134.599 us; speedup 1.0000x reference)
//
#include <hip/hip_runtime.h>

// Sinkhorn, fully register-resident. K = exp(-C/eps) = G (x) G (separable);
// G derived in-kernel from exact 1D slices of C. One block per batch, one
// kernel total. Wave w owns rows 6w..6w+5 (lane = column): Fa/Fb/m_src/m_tgt
// live in VGPRs. x-conv = pure-register: acc += Gc[j] * readlane(src[q], j)
// (Gc = G column in 48 loop-invariant VGPRs; intra-wave broadcast, no LDS,
// no smem, no barrier). y-conv: transpose through LDS (write 3x b64, read
// 12x b128 per wave), G rows via readlane(Grow[q], j). Double-buffered Tt
// -> 1 barrier per half-iteration (9 total). Pass 0 folded analytically.
// Cost pass: K o C = H(x)G + G(x)H, H-row/col rebuilt from Gc/Grow * C1d.
// R6 = R5 resubmit (container infra failure), hardened: device fn instead of
// macro, explicit min-waves launch bounds, outer loop unroll-capped.

#define SZ 48
#define SN 2304          // 48*48
#define LDT 52           // padded LDS row stride (208 B, 16B-aligned)
#define NBAT 32
#define NTHR 512         // 8 waves
#define NW 8
#define QB 6             // rows per wave (8*6 = 48)

__device__ __forceinline__ float rl(float v, int j) {
    return __int_as_float(__builtin_amdgcn_readlane(__float_as_int(v), j));
}

__device__ __forceinline__ float getc(const float4 v, int i) {
    return i == 0 ? v.x : i == 1 ? v.y : i == 2 ? v.z : v.w;
}

// one half-iteration: S = K*src (x-conv then y-conv), dst update in-place
__device__ __forceinline__ void half_iter(const float* __restrict__ Gc,
                                          const float* __restrict__ Grow,
                                          const float* __restrict__ src,
                                          float* __restrict__ dst,
                                          const float* __restrict__ mv,
                                          float* __restrict__ TT,
                                          int l, int lc, int r0) {
    float ac[QB];
    #pragma unroll
    for (int q = 0; q < QB; ++q) ac[q] = 0.f;
    #pragma unroll
    for (int j = 0; j < SZ; ++j) {
        #pragma unroll
        for (int q = 0; q < QB; ++q)
            ac[q] = fmaf(Gc[j], rl(src[q], j), ac[q]);
    }
    if (l < SZ) {
        *(float2*)&TT[lc * LDT + r0    ] = make_float2(ac[0], ac[1]);
        *(float2*)&TT[lc * LDT + r0 + 2] = make_float2(ac[2], ac[3]);
        *(float2*)&TT[lc * LDT + r0 + 4] = make_float2(ac[4], ac[5]);
    }
    __syncthreads();
    float4 qv[12];
    #pragma unroll
    for (int jc = 0; jc < 12; ++jc)
        qv[jc] = *(const float4*)&TT[lc * LDT + jc * 4];
    float s2[QB];
    #pragma unroll
    for (int q = 0; q < QB; ++q) s2[q] = 0.f;
    #pragma unroll
    for (int j = 0; j < SZ; ++j) {
        const float tj = getc(qv[j >> 2], j & 3);
        #pragma unroll
        for (int q = 0; q < QB; ++q)
            s2[q] = fmaf(rl(Grow[q], j), tj, s2[q]);
    }
    #pragma unroll
    for (int q = 0; q < QB; ++q) {
        const float yo = dst[q];
        dst[q] = mv[q] * yo / (yo * s2[q] + 1e-6f);
    }
}

__global__ __launch_bounds__(NTHR, 1) void k_all(const float* __restrict__ pred,
                                                 const float* __restrict__ tgt,
                                                 const float* __restrict__ C,
                                                 float* __restrict__ out) {
    __shared__ float LC[SZ * LDT];   // C1d, permanent
    __shared__ float TA[SZ * LDT];   // G at init; then Tt buffer A / T1t
    __shared__ float TB[SZ * LDT];   // Tt buffer B / T2t
    __shared__ float red[16];

    const int t = threadIdx.x;
    const int b = blockIdx.x;
    const int l = t & 63;
    const int w = t >> 6;
    const int r0 = w * QB;
    const int lc = (l < SZ) ? l : 0;

    // ---- stage C1d and G into LDS ----
    for (int i = t; i < SN; i += NTHR) {
        const int a = i / SZ, c = i - a * SZ;
        const float cv = C[(size_t)a * SZ * SN + (size_t)c * SZ];
        LC[a * LDT + c] = cv;
        TA[a * LDT + c] = expf(-100.f * cv);
    }
    __syncthreads();

    // ---- gather loop-invariant registers ----
    float Gc[SZ];                     // G column for this lane
    #pragma unroll
    for (int j = 0; j < SZ; ++j) Gc[j] = TA[j * LDT + lc];
    float Grow[QB], Crow[QB];         // this wave's G / C1d rows (lane-spread)
    #pragma unroll
    for (int q = 0; q < QB; ++q) {
        Grow[q] = TA[(r0 + q) * LDT + lc];
        Crow[q] = LC[(r0 + q) * LDT + lc];
    }
    float gs = 0.f;                   // gsl[lane] = sum_j G[j][lane]
    #pragma unroll
    for (int j = 0; j < SZ; ++j) gs += Gc[j];

    // ---- load mass planes (channel 0), block sums ----
    const float* __restrict__ pg = pred + (size_t)b * 3 * SN;
    const float* __restrict__ tg = tgt + (size_t)b * 3 * SN;
    float ms[QB], mt[QB];
    #pragma unroll
    for (int q = 0; q < QB; ++q) {
        ms[q] = pg[(r0 + q) * SZ + lc] + 1e-9f;
        mt[q] = tg[(r0 + q) * SZ + lc] + 1e-9f;
    }
    float sp = 0.f, st = 0.f;
    if (l < SZ) {
        #pragma unroll
        for (int q = 0; q < QB; ++q) { sp += ms[q]; st += mt[q]; }
    }
    #pragma unroll
    for (int off = 32; off; off >>= 1) {
        sp += __shfl_down(sp, off);
        st += __shfl_down(st, off);
    }
    if (l == 0) { red[w] = sp; red[8 + w] = st; }
    __syncthreads();   // also fences TA(G)/LC register-gather vs later writes
    float ps = 0.f, ts = 0.f;
    #pragma unroll
    for (int k = 0; k < NW; ++k) { ps += red[k]; ts += red[8 + k]; }

    // ---- normalize + folded pass 0: Fa = m_src/(gs[y]*gs[x]+1e-6), Fb=1 ----
    float Fa[QB], Fb[QB];
    #pragma unroll
    for (int q = 0; q < QB; ++q) {
        ms[q] /= ps;
        mt[q] /= ts;
        const float gr = rl(gs, r0 + q);    // gsl[row], uniform lane index
        Fa[q] = ms[q] / (gr * gs + 1e-6f);
        Fb[q] = 1.f;
    }

    // ---- 9 remaining half-iterations: B,A,B,A,B,A,B,A,B ----
    #pragma unroll 1
    for (int it = 0; it < 4; ++it) {
        half_iter(Gc, Grow, Fa, Fb, mt, TA, l, lc, r0);
        half_iter(Gc, Grow, Fb, Fa, ms, TB, l, lc, r0);
    }
    half_iter(Gc, Grow, Fa, Fb, mt, TA, l, lc, r0);
    __syncthreads();   // protect TA readers before final overwrites

    // ---- final: cost = sum Fa .* ((H(x)G + G(x)H) Fb) ----
    // stage 1: T1 = G-x-conv(Fb) -> TA, T2 = H-x-conv(Fb) -> TB
    {
        float4 cq[12];
        #pragma unroll
        for (int jc = 0; jc < 12; ++jc)
            cq[jc] = *(const float4*)&LC[lc * LDT + jc * 4];
        float t1[QB], t2[QB];
        #pragma unroll
        for (int q = 0; q < QB; ++q) { t1[q] = 0.f; t2[q] = 0.f; }
        #pragma unroll
        for (int j = 0; j < SZ; ++j) {
            const float cc = getc(cq[j >> 2], j & 3);
            const float hc = Gc[j] * cc;          // H[lane][j]
            #pragma unroll
            for (int q = 0; q < QB; ++q) {
                const float s = rl(Fb[q], j);
                t1[q] = fmaf(Gc[j], s, t1[q]);
                t2[q] = fmaf(hc,    s, t2[q]);
            }
        }
        if (l < SZ) {
            *(float2*)&TA[lc * LDT + r0    ] = make_float2(t1[0], t1[1]);
            *(float2*)&TA[lc * LDT + r0 + 2] = make_float2(t1[2], t1[3]);
            *(float2*)&TA[lc * LDT + r0 + 4] = make_float2(t1[4], t1[5]);
            *(float2*)&TB[lc * LDT + r0    ] = make_float2(t2[0], t2[1]);
            *(float2*)&TB[lc * LDT + r0 + 2] = make_float2(t2[2], t2[3]);
            *(float2*)&TB[lc * LDT + r0 + 4] = make_float2(t2[4], t2[5]);
        }
    }
    __syncthreads();

    // stage 2: U[yi][x] = sum_j H[yi][j]*T1[j][x] + G[yi][j]*T2[j][x]
    float part = 0.f;
    {
        float4 q1[12], q2[12];
        #pragma unroll
        for (int jc = 0; jc < 12; ++jc) {
            q1[jc] = *(const float4*)&TA[lc * LDT + jc * 4];
            q2[jc] = *(const float4*)&TB[lc * LDT + jc * 4];
        }
        float Hrow[QB];
        #pragma unroll
        for (int q = 0; q < QB; ++q) Hrow[q] = Grow[q] * Crow[q];
        float u[QB];
        #pragma unroll
        for (int q = 0; q < QB; ++q) u[q] = 0.f;
        #pragma unroll
        for (int j = 0; j < SZ; ++j) {
            const float a1 = getc(q1[j >> 2], j & 3);
            const float a2 = getc(q2[j >> 2], j & 3);
            #pragma unroll
            for (int q = 0; q < QB; ++q) {
                u[q] = fmaf(rl(Hrow[q], j), a1, u[q]);
                u[q] = fmaf(rl(Grow[q], j), a2, u[q]);
            }
        }
        if (l < SZ) {
            #pragma unroll
            for (int q = 0; q < QB; ++q) part = fmaf(Fa[q], u[q], part);
        }
    }
    #pragma unroll
    for (int off = 32; off; off >>= 1) part += __shfl_down(part, off);
    if (l == 0) red[w] = part;
    __syncthreads();
    if (t == 0) {
        float c = 0.f;
        #pragma unroll
        for (int k = 0; k < NW; ++k) c += red[k];
        out[b] = c;
    }
}

extern "C" void kernel_launch(void* const* d_in, const int* in_sizes, int n_in,
                              void* d_out, int out_size, void* d_ws, size_t ws_size,
                              hipStream_t stream) {
    const float* pred = (const float*)d_in[0];
    const float* tgt  = (const float*)d_in[1];
    const float* C    = (const float*)d_in[2];
    k_all<<<NBAT, NTHR, 0, stream>>>(pred, tgt, C, (float*)d_out);
}

// Round 7
// 115.691 us; speedup vs baseline: 1.1634x; 1.1634x over previous
//
#include <hip/hip_runtime.h>

// Sinkhorn via separable kernel: K = exp(-C/eps) = G (x) G (kron), with
// G[a][b] = exp(-100 * C1d[a][b]) read as exact 1D slices of the provided C
// (preserves reference's rounded dy^2). K.x = y-conv(G, x-conv(G, x)).
// Cost pass: K o C = H(x)G + G(x)H with H = G * C1d.
// One block per batch (32 blocks), whole chain in one kernel, state in LDS.
// R7 = the measured-best R2 structure (interleaved per-jc float4 LDS reads +
// plain wave-uniform global G row-loads + transposed Tt with lane-contiguous
// writes + folded pass 0), single controlled change: 12 -> 16 waves
// (YB 4 -> 3) for 4 waves/SIMD latency coverage. pk-fma and hoisted-load
// variants measured worse (R3/R4); readlane/register variant worse (R6).

#define SZ 48
#define SN 2304          // 48*48
#define LD 52            // padded LDS row stride (208 B, 16B-aligned)
#define NBAT 32
#define NTHR 1024        // 16 waves
#define NW 16
#define YB 3             // output rows per wave (16*3 = 48)

__global__ __launch_bounds__(256) void k_pre(const float* __restrict__ C,
                                             float* __restrict__ G,
                                             float* __restrict__ H) {
    const int idx = blockIdx.x * 256 + threadIdx.x;   // 9*256 = 2304 exactly
    const int a = idx / SZ;
    const int c = idx - a * SZ;
    const float cv = C[(size_t)a * SZ * SN + (size_t)c * SZ];
    const float g = expf(-100.f * cv);
    G[idx] = g;
    H[idx] = g * cv;
}

__device__ __forceinline__ float getc(const float4 v, int i) {
    return i == 0 ? v.x : i == 1 ? v.y : i == 2 ? v.z : v.w;
}

__global__ __launch_bounds__(NTHR) void k_sink(const float* __restrict__ pred,
                                               const float* __restrict__ tgt,
                                               const float* __restrict__ Gm,
                                               const float* __restrict__ Hm,
                                               float* __restrict__ out) {
    __shared__ float Fa[SZ * LD];    // alpha scaling
    __shared__ float Fb[SZ * LD];    // beta scaling (init 1)
    __shared__ float Fms[SZ * LD];   // mass_source; reused as T2t in final
    __shared__ float Fmt[SZ * LD];   // mass_target
    __shared__ float Tt[SZ * LD];    // conv intermediate, TRANSPOSED [xi][y]
    __shared__ float gsl[SZ];        // row sums of G (folded pass 0)
    __shared__ float red[32];

    const int t = threadIdx.x;
    const int b = blockIdx.x;
    const int l = t & 63;
    const int w = __builtin_amdgcn_readfirstlane(t >> 6);  // scalar wave id
    const int r0 = w * YB;                                 // wave's output rows

    // ---- init: G row sums, load channel-0 planes, sum, normalize ----
    if (t < SZ) {
        float s = 0.f;
        #pragma unroll 8
        for (int j = 0; j < SZ; ++j) s += Gm[t * SZ + j];
        gsl[t] = s;
    }
    const float* __restrict__ pg = pred + (size_t)b * 3 * SN;
    const float* __restrict__ tg = tgt + (size_t)b * 3 * SN;
    float sp = 0.f, st = 0.f;
    for (int i = t; i < SN; i += NTHR) {
        const float vp = pg[i] + 1e-9f;
        const float vt = tg[i] + 1e-9f;
        const int y = i / SZ, x = i - y * SZ;
        Fms[y * LD + x] = vp;
        Fmt[y * LD + x] = vt;
        sp += vp; st += vt;
    }
    #pragma unroll
    for (int off = 32; off; off >>= 1) {
        sp += __shfl_down(sp, off);
        st += __shfl_down(st, off);
    }
    if (l == 0) { red[w] = sp; red[16 + w] = st; }
    __syncthreads();
    float ps = 0.f, ts = 0.f;
    #pragma unroll
    for (int k = 0; k < NW; ++k) { ps += red[k]; ts += red[16 + k]; }
    // folded pass 0: Fa = m_src / (gs[y]*gs[x] + 1e-6), Fb = 1
    for (int i = t; i < SN; i += NTHR) {
        const int y = i / SZ, x = i - y * SZ;
        const float ms = Fms[y * LD + x] / ps;
        Fms[y * LD + x] = ms;
        Fmt[y * LD + x] /= ts;
        Fa[y * LD + x] = ms / (gsl[y] * gsl[x] + 1e-6f);
        Fb[y * LD + x] = 1.f;
    }
    __syncthreads();

    // ---- remaining 9 half-iterations (p=1..9) ----
    for (int p = 1; p < 10; ++p) {
        float* __restrict__ src = (p & 1) ? Fa : Fb;
        float* __restrict__ dst = (p & 1) ? Fb : Fa;
        const float* __restrict__ mv = (p & 1) ? Fmt : Fms;

        // step1 (x-conv): Tt[xi][y] = sum_j G[xi][j] * src[y][j]
        // lane l = y; interleaved: one b128 read per 4 j's between FMA groups
        if (l < SZ) {
            float a0 = 0.f, a1 = 0.f, a2 = 0.f;
            #pragma unroll
            for (int jc = 0; jc < 12; ++jc) {
                const float4 q = *(const float4*)&src[l * LD + jc * 4];
                #pragma unroll
                for (int jj = 0; jj < 4; ++jj) {
                    const int j = jc * 4 + jj;
                    const float g0 = Gm[j * SZ + r0];
                    const float g1 = Gm[j * SZ + r0 + 1];
                    const float g2 = Gm[j * SZ + r0 + 2];
                    const float v = getc(q, jj);
                    a0 = fmaf(g0, v, a0);
                    a1 = fmaf(g1, v, a1);
                    a2 = fmaf(g2, v, a2);
                }
            }
            Tt[(r0 + 0) * LD + l] = a0;    // lane-contiguous, conflict-free
            Tt[(r0 + 1) * LD + l] = a1;
            Tt[(r0 + 2) * LD + l] = a2;
        }
        __syncthreads();

        // step2 (y-conv) + fused update: S[yi][x] = sum_j G[yi][j]*Tt[x][j]
        if (l < SZ) {
            float a0 = 0.f, a1 = 0.f, a2 = 0.f;
            #pragma unroll
            for (int jc = 0; jc < 12; ++jc) {
                const float4 q = *(const float4*)&Tt[l * LD + jc * 4];
                #pragma unroll
                for (int jj = 0; jj < 4; ++jj) {
                    const int j = jc * 4 + jj;
                    const float g0 = Gm[j * SZ + r0];
                    const float g1 = Gm[j * SZ + r0 + 1];
                    const float g2 = Gm[j * SZ + r0 + 2];
                    const float v = getc(q, jj);
                    a0 = fmaf(g0, v, a0);
                    a1 = fmaf(g1, v, a1);
                    a2 = fmaf(g2, v, a2);
                }
            }
            const float s3[3] = {a0, a1, a2};
            #pragma unroll
            for (int k = 0; k < YB; ++k) {
                const int idx = (r0 + k) * LD + l;
                const float yo = dst[idx];
                dst[idx] = mv[idx] * yo / (yo * s3[k] + 1e-6f);
            }
        }
        __syncthreads();
    }

    // ---- final: cost = sum Fa .* ((H(x)G + G(x)H) applied to Fb) ----
    // stage 1: T1t = (G-x-conv(beta))^T in Tt, T2t = (H-x-conv(beta))^T in Fms
    if (l < SZ) {
        float t1[3] = {0.f, 0.f, 0.f}, t2[3] = {0.f, 0.f, 0.f};
        #pragma unroll
        for (int jc = 0; jc < 12; ++jc) {
            const float4 q = *(const float4*)&Fb[l * LD + jc * 4];
            #pragma unroll
            for (int jj = 0; jj < 4; ++jj) {
                const int j = jc * 4 + jj;
                const float v = getc(q, jj);
                #pragma unroll
                for (int k = 0; k < YB; ++k) {
                    t1[k] = fmaf(Gm[j * SZ + r0 + k], v, t1[k]);
                    t2[k] = fmaf(Hm[j * SZ + r0 + k], v, t2[k]);
                }
            }
        }
        #pragma unroll
        for (int k = 0; k < YB; ++k) {
            Tt [(r0 + k) * LD + l] = t1[k];
            Fms[(r0 + k) * LD + l] = t2[k];
        }
    }
    __syncthreads();

    // stage 2: U[yi][x] = sum_j H[yi][j]*T1t[x][j] + G[yi][j]*T2t[x][j]
    float part = 0.f;
    if (l < SZ) {
        float u[3] = {0.f, 0.f, 0.f};
        #pragma unroll
        for (int jc = 0; jc < 12; ++jc) {
            const float4 q1 = *(const float4*)&Tt [l * LD + jc * 4];
            const float4 q2 = *(const float4*)&Fms[l * LD + jc * 4];
            #pragma unroll
            for (int jj = 0; jj < 4; ++jj) {
                const int j = jc * 4 + jj;
                const float v1 = getc(q1, jj);
                const float v2 = getc(q2, jj);
                #pragma unroll
                for (int k = 0; k < YB; ++k) {
                    u[k] = fmaf(Hm[j * SZ + r0 + k], v1, u[k]);
                    u[k] = fmaf(Gm[j * SZ + r0 + k], v2, u[k]);
                }
            }
        }
        #pragma unroll
        for (int k = 0; k < YB; ++k)
            part = fmaf(Fa[(r0 + k) * LD + l], u[k], part);
    }
    #pragma unroll
    for (int off = 32; off; off >>= 1) part += __shfl_down(part, off);
    if (l == 0) red[w] = part;
    __syncthreads();
    if (t == 0) {
        float c = 0.f;
        #pragma unroll
        for (int k = 0; k < NW; ++k) c += red[k];
        out[b] = c;
    }
}

extern "C" void kernel_launch(void* const* d_in, const int* in_sizes, int n_in,
                              void* d_out, int out_size, void* d_ws, size_t ws_size,
                              hipStream_t stream) {
    const float* pred = (const float*)d_in[0];
    const float* tgt  = (const float*)d_in[1];
    const float* C    = (const float*)d_in[2];
    float* G = (float*)d_ws;          // 2304 floats
    float* H = G + SN;                // 2304 floats

    k_pre<<<9, 256, 0, stream>>>(C, G, H);
    k_sink<<<NBAT, NTHR, 0, stream>>>(pred, tgt, G, H, (float*)d_out);
}

// Round 8
// 106.559 us; speedup vs baseline: 1.2631x; 1.0857x over previous
//
#include <hip/hip_runtime.h>

// Sinkhorn via separable kernel: K = exp(-C/eps) = G (x) G (kron), with
// G[a][b] = exp(-100 * C1d[a][b]) from exact 1D slices of the provided C
// (preserves reference's rounded dy^2). K.x = y-conv(G, x-conv(G, x)).
// Cost pass: K o C = H(x)G + G(x)H with H = G * C1d.
// One block per batch (32 blocks), whole chain in ONE kernel, state in LDS.
// R8 = measured-best R2 structure (12 waves x YB=4 -> r0 16B-aligned,
// interleaved per-jc float4 LDS reads, lane-contiguous transposed-Tt writes,
// folded pass 0) + two changes: (1) G/H staged in LDS (192B rows; per-j
// fetch = one b128 same-address broadcast, conflict-free, replacing 864
// re-issued global dwordx4/wave of loop-invariant data), (2) k_pre fused
// (2 dispatches -> 1). 16-wave variants measured worse (R4/R7); readlane
// register variant worse (R6); pk-fma worse (R3).

#define SZ 48
#define SN 2304          // 48*48
#define LD 52            // padded LDS row stride (208 B, 16B-aligned)
#define NBAT 32
#define NTHR 768         // 12 waves
#define NW 12
#define YB 4             // output rows per wave (12*4 = 48)

__device__ __forceinline__ float getc(const float4 v, int i) {
    return i == 0 ? v.x : i == 1 ? v.y : i == 2 ? v.z : v.w;
}

__global__ __launch_bounds__(NTHR) void k_sink(const float* __restrict__ pred,
                                               const float* __restrict__ tgt,
                                               const float* __restrict__ C,
                                               float* __restrict__ out) {
    __shared__ float Fa[SZ * LD];    // alpha scaling
    __shared__ float Fb[SZ * LD];    // beta scaling (init 1)
    __shared__ float Fms[SZ * LD];   // mass_source; reused as T2t in final
    __shared__ float Fmt[SZ * LD];   // mass_target
    __shared__ float Tt[SZ * LD];    // conv intermediate, TRANSPOSED [xi][y]
    __shared__ float Gs[SZ * SZ];    // G, 192B rows (16B-aligned)
    __shared__ float Hs[SZ * SZ];    // H = G * C1d
    __shared__ float gsl[SZ];        // row sums of G (folded pass 0)
    __shared__ float red[32];

    const int t = threadIdx.x;
    const int b = blockIdx.x;
    const int l = t & 63;
    const int w = __builtin_amdgcn_readfirstlane(t >> 6);  // scalar wave id
    const int r0 = w * YB;                                 // wave's output rows

    // ---- stage G/H into LDS (fused k_pre) ----
    for (int i = t; i < SN; i += NTHR) {
        const int a = i / SZ, c = i - a * SZ;
        const float cv = C[(size_t)a * SZ * SN + (size_t)c * SZ];
        const float g = expf(-100.f * cv);
        Gs[a * SZ + c] = g;
        Hs[a * SZ + c] = g * cv;
    }

    // ---- load channel-0 planes, block sums ----
    const float* __restrict__ pg = pred + (size_t)b * 3 * SN;
    const float* __restrict__ tg = tgt + (size_t)b * 3 * SN;
    float sp = 0.f, st = 0.f;
    for (int i = t; i < SN; i += NTHR) {
        const float vp = pg[i] + 1e-9f;
        const float vt = tg[i] + 1e-9f;
        const int y = i / SZ, x = i - y * SZ;
        Fms[y * LD + x] = vp;
        Fmt[y * LD + x] = vt;
        sp += vp; st += vt;
    }
    #pragma unroll
    for (int off = 32; off; off >>= 1) {
        sp += __shfl_down(sp, off);
        st += __shfl_down(st, off);
    }
    if (l == 0) { red[w] = sp; red[16 + w] = st; }
    __syncthreads();                  // Gs/Hs, Fms/Fmt, red all visible

    // ---- G row sums (from LDS) ----
    if (t < SZ) {
        float s = 0.f;
        #pragma unroll 8
        for (int j = 0; j < SZ; ++j) s += Gs[t * SZ + j];
        gsl[t] = s;
    }
    float ps = 0.f, ts = 0.f;
    #pragma unroll
    for (int k = 0; k < NW; ++k) { ps += red[k]; ts += red[16 + k]; }
    __syncthreads();                  // gsl visible

    // folded pass 0: Fa = m_src / (gs[y]*gs[x] + 1e-6), Fb = 1
    for (int i = t; i < SN; i += NTHR) {
        const int y = i / SZ, x = i - y * SZ;
        const float ms = Fms[y * LD + x] / ps;
        Fms[y * LD + x] = ms;
        Fmt[y * LD + x] /= ts;
        Fa[y * LD + x] = ms / (gsl[y] * gsl[x] + 1e-6f);
        Fb[y * LD + x] = 1.f;
    }
    __syncthreads();

    // ---- remaining 9 half-iterations (p=1..9) ----
    for (int p = 1; p < 10; ++p) {
        float* __restrict__ src = (p & 1) ? Fa : Fb;
        float* __restrict__ dst = (p & 1) ? Fb : Fa;
        const float* __restrict__ mv = (p & 1) ? Fmt : Fms;

        // step1 (x-conv): Tt[xi][y] = sum_j G[xi][j] * src[y][j]
        // lane l = y; per j: one b128 broadcast of G[j][r0..r0+3] (G symm)
        if (l < SZ) {
            float a0 = 0.f, a1 = 0.f, a2 = 0.f, a3 = 0.f;
            #pragma unroll
            for (int jc = 0; jc < 12; ++jc) {
                const float4 q = *(const float4*)&src[l * LD + jc * 4];
                #pragma unroll
                for (int jj = 0; jj < 4; ++jj) {
                    const int j = jc * 4 + jj;
                    const float4 g = *(const float4*)&Gs[j * SZ + r0];
                    const float v = getc(q, jj);
                    a0 = fmaf(g.x, v, a0);
                    a1 = fmaf(g.y, v, a1);
                    a2 = fmaf(g.z, v, a2);
                    a3 = fmaf(g.w, v, a3);
                }
            }
            Tt[(r0 + 0) * LD + l] = a0;    // lane-contiguous, conflict-free
            Tt[(r0 + 1) * LD + l] = a1;
            Tt[(r0 + 2) * LD + l] = a2;
            Tt[(r0 + 3) * LD + l] = a3;
        }
        __syncthreads();

        // step2 (y-conv) + fused update: S[yi][x] = sum_j G[yi][j]*Tt[x][j]
        if (l < SZ) {
            float a0 = 0.f, a1 = 0.f, a2 = 0.f, a3 = 0.f;
            #pragma unroll
            for (int jc = 0; jc < 12; ++jc) {
                const float4 q = *(const float4*)&Tt[l * LD + jc * 4];
                #pragma unroll
                for (int jj = 0; jj < 4; ++jj) {
                    const int j = jc * 4 + jj;
                    const float4 g = *(const float4*)&Gs[j * SZ + r0];
                    const float v = getc(q, jj);
                    a0 = fmaf(g.x, v, a0);
                    a1 = fmaf(g.y, v, a1);
                    a2 = fmaf(g.z, v, a2);
                    a3 = fmaf(g.w, v, a3);
                }
            }
            const float s4[4] = {a0, a1, a2, a3};
            #pragma unroll
            for (int k = 0; k < YB; ++k) {
                const int idx = (r0 + k) * LD + l;
                const float yo = dst[idx];
                dst[idx] = mv[idx] * yo / (yo * s4[k] + 1e-6f);
            }
        }
        __syncthreads();
    }

    // ---- final: cost = sum Fa .* ((H(x)G + G(x)H) applied to Fb) ----
    // stage 1: T1t = (G-x-conv(beta))^T in Tt, T2t = (H-x-conv(beta))^T in Fms
    if (l < SZ) {
        float t1[4] = {0.f, 0.f, 0.f, 0.f}, t2[4] = {0.f, 0.f, 0.f, 0.f};
        #pragma unroll
        for (int jc = 0; jc < 12; ++jc) {
            const float4 q = *(const float4*)&Fb[l * LD + jc * 4];
            #pragma unroll
            for (int jj = 0; jj < 4; ++jj) {
                const int j = jc * 4 + jj;
                const float4 g = *(const float4*)&Gs[j * SZ + r0];
                const float4 h = *(const float4*)&Hs[j * SZ + r0];
                const float v = getc(q, jj);
                t1[0] = fmaf(g.x, v, t1[0]);  t1[1] = fmaf(g.y, v, t1[1]);
                t1[2] = fmaf(g.z, v, t1[2]);  t1[3] = fmaf(g.w, v, t1[3]);
                t2[0] = fmaf(h.x, v, t2[0]);  t2[1] = fmaf(h.y, v, t2[1]);
                t2[2] = fmaf(h.z, v, t2[2]);  t2[3] = fmaf(h.w, v, t2[3]);
            }
        }
        #pragma unroll
        for (int k = 0; k < YB; ++k) {
            Tt [(r0 + k) * LD + l] = t1[k];
            Fms[(r0 + k) * LD + l] = t2[k];
        }
    }
    __syncthreads();

    // stage 2: U[yi][x] = sum_j H[yi][j]*T1t[x][j] + G[yi][j]*T2t[x][j]
    float part = 0.f;
    if (l < SZ) {
        float u[4] = {0.f, 0.f, 0.f, 0.f};
        #pragma unroll
        for (int jc = 0; jc < 12; ++jc) {
            const float4 q1 = *(const float4*)&Tt [l * LD + jc * 4];
            const float4 q2 = *(const float4*)&Fms[l * LD + jc * 4];
            #pragma unroll
            for (int jj = 0; jj < 4; ++jj) {
                const int j = jc * 4 + jj;
                const float4 g = *(const float4*)&Gs[j * SZ + r0];
                const float4 h = *(const float4*)&Hs[j * SZ + r0];
                const float v1 = getc(q1, jj);
                const float v2 = getc(q2, jj);
                u[0] = fmaf(h.x, v1, u[0]);  u[1] = fmaf(h.y, v1, u[1]);
                u[2] = fmaf(h.z, v1, u[2]);  u[3] = fmaf(h.w, v1, u[3]);
                u[0] = fmaf(g.x, v2, u[0]);  u[1] = fmaf(g.y, v2, u[1]);
                u[2] = fmaf(g.z, v2, u[2]);  u[3] = fmaf(g.w, v2, u[3]);
            }
        }
        #pragma unroll
        for (int k = 0; k < YB; ++k)
            part = fmaf(Fa[(r0 + k) * LD + l], u[k], part);
    }
    #pragma unroll
    for (int off = 32; off; off >>= 1) part += __shfl_down(part, off);
    if (l == 0) red[w] = part;
    __syncthreads();
    if (t == 0) {
        float c = 0.f;
        #pragma unroll
        for (int k = 0; k < NW; ++k) c += red[k];
        out[b] = c;
    }
}

extern "C" void kernel_launch(void* const* d_in, const int* in_sizes, int n_in,
                              void* d_out, int out_size, void* d_ws, size_t ws_size,
                              hipStream_t stream) {
    const float* pred = (const float*)d_in[0];
    const float* tgt  = (const float*)d_in[1];
    const float* C    = (const float*)d_in[2];
    k_sink<<<NBAT, NTHR, 0, stream>>>(pred, tgt, C, (float*)d_out);
}